// Round 1
// baseline (326.871 us; speedup 1.0000x reference)
//
#include <hip/hip_runtime.h>

// LengthRegulator: the predictor path in the reference is dead code
// (durations = target_durations overrides _pred). Outputs:
//   [0] padded [B, F, D] f32 = expand(x, target_durations)
//   [1] durations [B, T]     = target_durations (written as float values;
//       harness reads the whole d_out as float32)

#define B_ 8
#define T_ 1024
#define D_ 1024
#define F_ 8192   // MAX_FRAMES = T * DMAX

// Kernel A: per-batch inclusive scan of durations (LDS Hillis-Steele),
// scatter token index into tok_map[b, f] for f in [cum[t-1], cum[t]),
// -1 for invalid tail frames; also emit durations output chunk as float.
__global__ void __launch_bounds__(1024) dur_scan_kernel(
    const int* __restrict__ dur,     // [B, T]
    int* __restrict__ tok_map,       // [B, F] (workspace)
    float* __restrict__ out_dur)     // [B, T] (tail of d_out, float view)
{
    __shared__ int s[T_];
    const int b = blockIdx.x;
    const int t = threadIdx.x;

    const int d = dur[b * T_ + t];
    out_dur[b * T_ + t] = (float)d;

    s[t] = d;
    __syncthreads();
    // inclusive scan over T_=1024
    #pragma unroll
    for (int off = 1; off < T_; off <<= 1) {
        int v = (t >= off) ? s[t - off] : 0;
        __syncthreads();
        s[t] += v;
        __syncthreads();
    }

    const int cum_t    = s[t];
    const int cum_prev = (t > 0) ? s[t - 1] : 0;
    const int total    = s[T_ - 1];

    int* tm = tok_map + b * F_;
    // frames covered by token t  (searchsorted side="right" semantics:
    // frame f -> token t iff cum[t-1] <= f < cum[t])
    for (int f = cum_prev; f < cum_t; ++f) tm[f] = t;
    // invalid tail -> -1 (strided fill by all threads)
    for (int f = total + t; f < F_; f += T_) tm[f] = -1;
}

// Kernel B: one block per output frame row. One uniform tok_map load,
// then a float4-coalesced 4 KiB row copy (or zero-fill if invalid).
__global__ void __launch_bounds__(256) expand_kernel(
    const float* __restrict__ x,      // [B, T, D]
    const int* __restrict__ tok_map,  // [B, F]
    float* __restrict__ out)          // [B, F, D]
{
    const int bf  = blockIdx.x;          // b * F_ + f
    const int b   = bf >> 13;            // F_ = 8192
    const int tok = tok_map[bf];

    float4* dst = reinterpret_cast<float4*>(out)
                + (size_t)bf * (D_ / 4) + threadIdx.x;
    if (tok < 0) {
        *dst = make_float4(0.f, 0.f, 0.f, 0.f);
    } else {
        const float4* src = reinterpret_cast<const float4*>(x)
                          + ((size_t)b * T_ + (size_t)tok) * (D_ / 4) + threadIdx.x;
        *dst = *src;
    }
}

extern "C" void kernel_launch(void* const* d_in, const int* in_sizes, int n_in,
                              void* d_out, int out_size, void* d_ws, size_t ws_size,
                              hipStream_t stream)
{
    const float* x   = (const float*)d_in[0];
    const int*   dur = (const int*)d_in[1];
    // d_in[2..11] (conv/LN/linear weights) are dead code in the reference.

    float* out     = (float*)d_out;
    float* out_dur = out + (size_t)B_ * F_ * D_;   // durations chunk
    int*   tok_map = (int*)d_ws;                   // B_*F_*4 = 256 KiB scratch

    dur_scan_kernel<<<B_, T_, 0, stream>>>(dur, tok_map, out_dur);
    expand_kernel<<<B_ * F_, 256, 0, stream>>>(x, tok_map, out);
}